// Round 10
// baseline (67.649 us; speedup 1.0000x reference)
//
#include <hip/hip_runtime.h>
#include <math.h>

// (b,n,h,d) = (4,8192,8,64), fp32.
// R10: BYTE-SET EQUALIZATION. R1-R9 falsified MLP/occupancy/coupling/DMA/
// segment-shape; the invariant was the byte-set: each group only touches a
// fixed offset-mod-2KB slice (g0: 0-767B of all rows, g1: 768-1535B of odd
// rows, g2: 1536-2047B of %4==2 rows) -> fixed channel subset -> ~2.4 TB/s.
// pass3 (touches all offsets) runs ~19 TB/s. Here ONE wave visits ONE row,
// computes ALL applicable groups, loads/stores FULL 2KB rows (full spread),
// zero-fills uncovered head slots (pass3 scale keeps them 0).
#define NB 4
#define NN 8192
#define NH 8
#define ND 64
#define ROWF 512                // floats per (b,pos) row = 2KB
#define T_PER_WAVE 16
#define N_BLOCKS_P1 512         // 2048 waves, 512 per batch, 16 rows each
#define N_WAVES_P1 2048
#define NPART 512               // per-wave partial: 8 heads x 64 d

__device__ __forceinline__ float dot4(float4 a, float4 b) {
    return a.x * b.x + a.y * b.y + a.z * b.z + a.w * b.w;
}
__device__ __forceinline__ float4 shfl4(float4 v, int src) {
    return make_float4(__shfl(v.x, src), __shfl(v.y, src),
                       __shfl(v.z, src), __shfl(v.w, src));
}
__device__ __forceinline__ void bfly16(float& a) {
    a += __shfl_xor(a, 8); a += __shfl_xor(a, 4);
    a += __shfl_xor(a, 2); a += __shfl_xor(a, 1);
}

__global__ __launch_bounds__(256)
void sda_pass1(const float* __restrict__ Q, const float* __restrict__ K,
               const float* __restrict__ V, float* __restrict__ out,
               float* __restrict__ partials)
{
    const int w    = threadIdx.x >> 6;
    const int lane = threadIdx.x & 63;
    const int sg   = lane >> 4;       // sub-group = head slot (A: h=sg, B: h=4+sg)
    const int l15  = lane & 15;       // d-slice [4*l15, 4*l15+4)
    const int wid  = blockIdx.x * 4 + w;
    const int b    = wid >> 9;        // 512 waves per batch
    const int j0   = (wid & 511) * T_PER_WAVE;

    float4 xsA = make_float4(0.f, 0.f, 0.f, 0.f);
    float4 xsB = make_float4(0.f, 0.f, 0.f, 0.f);

    for (int t = 0; t < T_PER_WAVE; ++t) {
        const int pos = j0 + t;
        const int p4  = pos & 3;
        const size_t rb = ((size_t)b * NN + pos) * ROWF;

        // full-row loads: lane L holds floats [4L,4L+4) (head L>>4) and
        // [256+4L, ..) (head 4+(L>>4)). Contiguous 1KB per instruction.
        const float4 qA = *(const float4*)(Q + rb + 4 * lane);
        const float4 kA = *(const float4*)(K + rb + 4 * lane);
        const float4 vA = *(const float4*)(V + rb + 4 * lane);
        float4 qB, kB, vB;
        if (p4 != 0) {      // B-half only needed when g1 or g2 active
            qB = *(const float4*)(Q + rb + 256 + 4 * lane);
            kB = *(const float4*)(K + rb + 256 + 4 * lane);
            vB = *(const float4*)(V + rb + 256 + 4 * lane);
        } else {
            qB = kB = vB = make_float4(0.f, 0.f, 0.f, 0.f);
        }

        float4 aA = make_float4(0.f, 0.f, 0.f, 0.f);
        float4 aB = make_float4(0.f, 0.f, 0.f, 0.f);

        // ---- group 0 (heads 0-2), every position; q = head sg (lanes sg<3) ----
        {
            const float4 K0 = shfl4(kA, l15), K1 = shfl4(kA, 16 + l15),
                         K2 = shfl4(kA, 32 + l15);
            float m0 = dot4(qA, K0), m1 = dot4(qA, K1), m2 = dot4(qA, K2);
            bfly16(m0); bfly16(m1); bfly16(m2);
            m0 *= 0.125f; m1 *= 0.125f; m2 *= 0.125f;
            const float mm = fmaxf(m0, fmaxf(m1, m2));
            const float e0 = __expf(m0 - mm), e1 = __expf(m1 - mm), e2 = __expf(m2 - mm);
            const float rs = 1.f / (e0 + e1 + e2);
            const float w0 = e0 * rs, w1 = e1 * rs, w2 = e2 * rs;
            const float4 V0 = shfl4(vA, l15), V1 = shfl4(vA, 16 + l15),
                         V2 = shfl4(vA, 32 + l15);
            float4 x;
            x.x = w0 * V0.x + w1 * V1.x + w2 * V2.x;
            x.y = w0 * V0.y + w1 * V1.y + w2 * V2.y;
            x.z = w0 * V0.z + w1 * V1.z + w2 * V2.z;
            x.w = w0 * V0.w + w1 * V1.w + w2 * V2.w;
            if (sg < 3) aA = x;
        }

        // ---- group 1 (heads 3-5), pos odd; q-slots: sg3*A, sg0*B, sg1*B ----
        if (pos & 1) {
            const float4 K3 = shfl4(kA, 48 + l15), K4 = shfl4(kB, l15),
                         K5 = shfl4(kB, 16 + l15);
            const float4 qg = (sg == 3) ? qA : qB;
            float m3 = dot4(qg, K3), m4 = dot4(qg, K4), m5 = dot4(qg, K5);
            bfly16(m3); bfly16(m4); bfly16(m5);
            m3 *= 0.125f; m4 *= 0.125f; m5 *= 0.125f;
            const float mm = fmaxf(m3, fmaxf(m4, m5));
            const float e3 = __expf(m3 - mm), e4 = __expf(m4 - mm), e5 = __expf(m5 - mm);
            const float rs = 1.f / (e3 + e4 + e5);
            const float w3 = e3 * rs, w4 = e4 * rs, w5 = e5 * rs;
            const float4 V3 = shfl4(vA, 48 + l15), V4 = shfl4(vB, l15),
                         V5 = shfl4(vB, 16 + l15);
            float4 x;
            x.x = w3 * V3.x + w4 * V4.x + w5 * V5.x;
            x.y = w3 * V3.y + w4 * V4.y + w5 * V5.y;
            x.z = w3 * V3.z + w4 * V4.z + w5 * V5.z;
            x.w = w3 * V3.w + w4 * V4.w + w5 * V5.w;
            if (sg == 3) aA = x;
            if (sg < 2)  aB = x;
        }

        // ---- group 2 (heads 6,7), pos%4==2; q-slots: sg2*B, sg3*B ----
        if (p4 == 2) {
            const float4 K6 = shfl4(kB, 32 + l15), K7 = shfl4(kB, 48 + l15);
            float m6 = dot4(qB, K6), m7 = dot4(qB, K7);
            bfly16(m6); bfly16(m7);
            m6 *= 0.125f; m7 *= 0.125f;
            const float mm = fmaxf(m6, m7);
            const float e6 = __expf(m6 - mm), e7 = __expf(m7 - mm);
            const float rs = 1.f / (e6 + e7);
            const float w6 = e6 * rs, w7 = e7 * rs;
            const float4 V6 = shfl4(vB, 32 + l15), V7 = shfl4(vB, 48 + l15);
            float4 x;
            x.x = w6 * V6.x + w7 * V7.x;
            x.y = w6 * V6.y + w7 * V7.y;
            x.z = w6 * V6.z + w7 * V7.z;
            x.w = w6 * V6.w + w7 * V7.w;
            if (sg >= 2) aB = x;
        }

        // full-row store (2KB, zeros in uncovered head slots)
        *(float4*)(out + rb + 4 * lane)       = aA;
        *(float4*)(out + rb + 256 + 4 * lane) = aB;
        xsA.x += aA.x; xsA.y += aA.y; xsA.z += aA.z; xsA.w += aA.w;
        xsB.x += aB.x; xsB.y += aB.y; xsB.z += aB.z; xsB.w += aB.w;
    }

    // lane owns (head sg, dslice) and (head 4+sg, dslice) exclusively
    *(float4*)(partials + (size_t)wid * NPART + sg * 64 + 4 * l15)       = xsA;
    *(float4*)(partials + (size_t)wid * NPART + (4 + sg) * 64 + 4 * l15) = xsB;
}

// pass2a: 256 blocks = (b,h)(32) x slice(8); each reduces 64 wave-partials.
__global__ __launch_bounds__(256)
void sda_pass2a(const float* __restrict__ partials, float* __restrict__ partial2)
{
    const int bid   = blockIdx.x;
    const int bh    = bid >> 3;
    const int slice = bid & 7;
    const int b     = bh >> 3;
    const int h     = bh & 7;
    const int d     = threadIdx.x & 63;
    const int part  = threadIdx.x >> 6;
    const int w0    = b * 512 + slice * 64;
    float s = 0.f;
    #pragma unroll 4
    for (int c = part; c < 64; c += 4)
        s += partials[(size_t)(w0 + c) * NPART + h * 64 + d];
    __shared__ float sred[4][64];
    sred[part][d] = s;
    __syncthreads();
    if (part == 0)
        partial2[(size_t)bid * 64 + d] = sred[0][d] + sred[1][d] + sred[2][d] + sred[3][d];
}

__global__ __launch_bounds__(256)
void sda_pass2b(const float* __restrict__ partial2, float* __restrict__ inv)
{
    const int t = blockIdx.x * 256 + threadIdx.x;   // 2048 = bh*64 + d
    if (t >= NB * NH * ND) return;
    const int bh = t >> 6;
    const int d  = t & 63;
    float s = 0.f;
    #pragma unroll
    for (int sl = 0; sl < 8; ++sl)
        s += partial2[(size_t)(bh * 8 + sl) * 64 + d];
    inv[t] = 1.f / (3.f * (s + 1e-8f));
}

// pass3: branch-free full-spread scale; uncovered slots are 0 -> stay 0.
__global__ __launch_bounds__(256)
void sda_pass3(float* __restrict__ out, const float* __restrict__ inv)
{
    const int total4 = NB * NN * NH * ND / 4;   // 4,194,304 float4s
    for (int idx = blockIdx.x * 256 + threadIdx.x; idx < total4;
         idx += gridDim.x * 256) {
        const int d4 = idx & 15;
        const int h  = (idx >> 4) & 7;
        const int b  = idx >> 20;
        const float4 v = ((const float4*)out)[idx];
        const float4 f = ((const float4*)inv)[(b * 8 + h) * 16 + d4];
        ((float4*)out)[idx] = make_float4(v.x * f.x, v.y * f.y, v.z * f.z, v.w * f.w);
    }
}

extern "C" void kernel_launch(void* const* d_in, const int* in_sizes, int n_in,
                              void* d_out, int out_size, void* d_ws, size_t ws_size,
                              hipStream_t stream)
{
    const float* Q = (const float*)d_in[0];
    const float* K = (const float*)d_in[1];
    const float* V = (const float*)d_in[2];
    float* out      = (float*)d_out;
    float* partials = (float*)d_ws;                            // 2048*512*4 = 4 MB
    float* partial2 = partials + (size_t)N_WAVES_P1 * NPART;   // +16384 floats
    float* inv      = partial2 + 256 * 64;                     // +2048 floats

    hipLaunchKernelGGL(sda_pass1,  dim3(N_BLOCKS_P1), dim3(256), 0, stream,
                       Q, K, V, out, partials);
    hipLaunchKernelGGL(sda_pass2a, dim3(256), dim3(256), 0, stream, partials, partial2);
    hipLaunchKernelGGL(sda_pass2b, dim3(8),   dim3(256), 0, stream, partial2, inv);
    hipLaunchKernelGGL(sda_pass3,  dim3(2048), dim3(256), 0, stream, out, inv);
}

// Round 11
// 53.319 us; speedup vs baseline: 1.2688x; 1.2688x over previous
//
#include <hip/hip_runtime.h>
#include <math.h>

// (b,n,h,d) = (4,8192,8,64), fp32.
// Groups: i=0: g=3,r=1,off=0,hmin=0,seg=2048  -> 8192 covered pos/b
//         i=1: g=3,r=2,off=1,hmin=3,seg=4096  -> 4096 covered pos/b (pos%2==1)
//         i=2: g=2,r=4,off=2,hmin=6,seg=8192  -> 2048 covered pos/b (pos%4==2)
#define NB 4
#define NN 8192
#define NH 8
#define ND 64
#define NPART_STRIDE 192        // per-WAVE partial: g*64 floats (max g=3)
#define N_BLOCKS_P1 448         // 1792 waves: g0 1024, g1 512, g2 256
#define N_WAVES_P1  1792

// R11: 8-LANES-PER-POSITION. R1-R10 falsified every memory-side theory
// (MLP/occupancy/coupling/DMA/persistence/segment-shape/byte-set); the
// invariant was the per-position dependent chain: 4-step shfl butterfly
// (~440cy serial DS latency) + 9 exps per position between load and store.
// Here each lane owns 8 dims: butterfly is 3 steps; exp/softmax are wave-ops
// covering 8 positions at once (1.1 exp/pos); V loads after softmax (reg
// reuse); PV is a pure independent FMA stream. One variable vs R6.

__device__ __forceinline__ float dot4(float4 a, float4 b) {
    return a.x * b.x + a.y * b.y + a.z * b.z + a.w * b.w;
}

template<int G>
__device__ __forceinline__ void pass1_work(
    const float* __restrict__ Q, const float* __restrict__ K,
    const float* __restrict__ V, float* __restrict__ out,
    float* __restrict__ partials,
    int b, int wave_local, int wid, int r, int off, int hmin, int seglen)
{
    const int lane = threadIdx.x & 63;
    const int p8   = lane >> 3;     // position slot 0..7
    const int d8   = lane & 7;      // dim slice [8*d8, 8*d8+8)

    float4 xs[G][2];
    #pragma unroll
    for (int q = 0; q < G; ++q) {
        xs[q][0] = make_float4(0.f, 0.f, 0.f, 0.f);
        xs[q][1] = make_float4(0.f, 0.f, 0.f, 0.f);
    }

    #pragma unroll 2
    for (int t = 0; t < 4; ++t) {
        const int j   = wave_local * 32 + t * 8 + p8;
        const int pos = (j >> 11) * seglen + off + (j & 2047) * r;
        const size_t rb = (((size_t)b * NN + pos) * NH + hmin) * ND + 8 * d8;

        // Q,K for all G heads: lane's 8 dims = 2 float4 per head
        float4 qv[G][2], kv[G][2];
        #pragma unroll
        for (int q = 0; q < G; ++q) {
            qv[q][0] = *(const float4*)(Q + rb + q * ND);
            qv[q][1] = *(const float4*)(Q + rb + q * ND + 4);
            kv[q][0] = *(const float4*)(K + rb + q * ND);
            kv[q][1] = *(const float4*)(K + rb + q * ND + 4);
        }

        // 9 (or 4) dots over this lane's 8 dims, then 3-step butterfly
        float sc[G][G];
        #pragma unroll
        for (int q = 0; q < G; ++q)
            #pragma unroll
            for (int k = 0; k < G; ++k)
                sc[q][k] = dot4(qv[q][0], kv[k][0]) + dot4(qv[q][1], kv[k][1]);
        #pragma unroll
        for (int o = 4; o >= 1; o >>= 1)
            #pragma unroll
            for (int q = 0; q < G; ++q)
                #pragma unroll
                for (int k = 0; k < G; ++k)
                    sc[q][k] += __shfl_xor(sc[q][k], o);

        // softmax over k — wave-ops covering all 8 positions at once
        #pragma unroll
        for (int q = 0; q < G; ++q) {
            float m = -INFINITY;
            #pragma unroll
            for (int k = 0; k < G; ++k) { sc[q][k] *= 0.125f; m = fmaxf(m, sc[q][k]); }
            float ssum = 0.f;
            #pragma unroll
            for (int k = 0; k < G; ++k) { sc[q][k] = __expf(sc[q][k] - m); ssum += sc[q][k]; }
            const float rs = 1.f / ssum;
            #pragma unroll
            for (int k = 0; k < G; ++k) sc[q][k] *= rs;
        }

        // V loads AFTER softmax (K registers retire; peak VGPR stays bounded)
        float4 vv[G][2];
        #pragma unroll
        for (int q = 0; q < G; ++q) {
            vv[q][0] = *(const float4*)(V + rb + q * ND);
            vv[q][1] = *(const float4*)(V + rb + q * ND + 4);
        }

        // PV: independent FMA stream; store lane's 8 dims per head
        #pragma unroll
        for (int q = 0; q < G; ++q) {
            float4 x0 = make_float4(0.f, 0.f, 0.f, 0.f);
            float4 x1 = make_float4(0.f, 0.f, 0.f, 0.f);
            #pragma unroll
            for (int k = 0; k < G; ++k) {
                const float aw = sc[q][k];
                x0.x += aw * vv[k][0].x; x0.y += aw * vv[k][0].y;
                x0.z += aw * vv[k][0].z; x0.w += aw * vv[k][0].w;
                x1.x += aw * vv[k][1].x; x1.y += aw * vv[k][1].y;
                x1.z += aw * vv[k][1].z; x1.w += aw * vv[k][1].w;
            }
            *(float4*)(out + rb + q * ND)     = x0;
            *(float4*)(out + rb + q * ND + 4) = x1;
            xs[q][0].x += x0.x; xs[q][0].y += x0.y; xs[q][0].z += x0.z; xs[q][0].w += x0.w;
            xs[q][1].x += x1.x; xs[q][1].y += x1.y; xs[q][1].z += x1.z; xs[q][1].w += x1.w;
        }
    }

    // cross-position reduce: lanes with same d8 across p8 slots (xor 8,16,32)
    #pragma unroll
    for (int o = 8; o <= 32; o <<= 1)
        #pragma unroll
        for (int q = 0; q < G; ++q) {
            xs[q][0].x += __shfl_xor(xs[q][0].x, o); xs[q][0].y += __shfl_xor(xs[q][0].y, o);
            xs[q][0].z += __shfl_xor(xs[q][0].z, o); xs[q][0].w += __shfl_xor(xs[q][0].w, o);
            xs[q][1].x += __shfl_xor(xs[q][1].x, o); xs[q][1].y += __shfl_xor(xs[q][1].y, o);
            xs[q][1].z += __shfl_xor(xs[q][1].z, o); xs[q][1].w += __shfl_xor(xs[q][1].w, o);
        }

    if (lane < 8) {   // p8==0 lanes: lane d8 owns dims [8*d8, 8*d8+8) of each head
        #pragma unroll
        for (int q = 0; q < G; ++q) {
            *(float4*)(partials + (size_t)wid * NPART_STRIDE + q * 64 + 8 * d8)     = xs[q][0];
            *(float4*)(partials + (size_t)wid * NPART_STRIDE + q * 64 + 8 * d8 + 4) = xs[q][1];
        }
    }
}

__global__ __launch_bounds__(256)
void sda_pass1(const float* __restrict__ Q, const float* __restrict__ K,
               const float* __restrict__ V, float* __restrict__ out,
               float* __restrict__ partials)
{
    const int bid = blockIdx.x;
    const int w   = threadIdx.x >> 6;
    const int wid = bid * 4 + w;
    if (bid < 256) {                       // group 0: b = bid>>6, 64 blocks/b
        const int b = bid >> 6, wl = (bid & 63) * 4 + w;
        pass1_work<3>(Q, K, V, out, partials, b, wl, wid, 1, 0, 0, 2048);
    } else if (bid < 384) {                // group 1: 32 blocks/b
        const int loc = bid - 256;
        const int b = loc >> 5, wl = (loc & 31) * 4 + w;
        pass1_work<3>(Q, K, V, out, partials, b, wl, wid, 2, 1, 3, 4096);
    } else {                               // group 2: 16 blocks/b
        const int loc = bid - 384;
        const int b = loc >> 4, wl = (loc & 15) * 4 + w;
        pass1_work<2>(Q, K, V, out, partials, b, wl, wid, 4, 2, 6, 8192);
    }
}

// pass2a: 256 blocks = (bh 0..31) x (slice 0..7); coalesced wave-partial reduce.
__global__ __launch_bounds__(256)
void sda_pass2a(const float* __restrict__ partials, float* __restrict__ partial2)
{
    const int bid   = blockIdx.x;
    const int bh    = bid >> 3;
    const int slice = bid & 7;
    const int b     = bh >> 3;
    const int h     = bh & 7;
    const int d     = threadIdx.x & 63;
    const int part  = threadIdx.x >> 6;   // 4-way split of the slice
    int qi, wstart, cnt;
    if (h < 3)      { qi = h;     wstart = b * 256;        cnt = 256; }
    else if (h < 6) { qi = h - 3; wstart = 1024 + b * 128; cnt = 128; }
    else            { qi = h - 6; wstart = 1536 + b * 64;  cnt = 64;  }
    const int len = cnt >> 3;             // 32 / 16 / 8
    const int c0  = wstart + slice * len;
    float s = 0.f;
    #pragma unroll 4
    for (int c = part; c < len; c += 4)
        s += partials[(size_t)(c0 + c) * NPART_STRIDE + qi * 64 + d];
    __shared__ float sred[4][64];
    sred[part][d] = s;
    __syncthreads();
    if (part == 0)
        partial2[(size_t)bid * 64 + d] = sred[0][d] + sred[1][d] + sred[2][d] + sred[3][d];
}

// pass2b: finish 8 slice-partials per (b,h,d) -> inv
__global__ __launch_bounds__(256)
void sda_pass2b(const float* __restrict__ partial2, float* __restrict__ inv)
{
    const int t = blockIdx.x * 256 + threadIdx.x;   // 2048 = bh*64 + d
    if (t >= NB * NH * ND) return;
    const int bh = t >> 6;
    const int d  = t & 63;
    float s = 0.f;
    #pragma unroll
    for (int sl = 0; sl < 8; ++sl)
        s += partial2[(size_t)(bh * 8 + sl) * 64 + d];
    inv[t] = 1.f / (3.f * (s + 1e-8f));
}

__global__ __launch_bounds__(256)
void sda_pass3(float* __restrict__ out, const float* __restrict__ inv)
{
    const int total4 = NB * NN * NH * ND / 4;   // 4,194,304 float4s
    for (int idx = blockIdx.x * 256 + threadIdx.x; idx < total4;
         idx += gridDim.x * 256) {
        const int d4  = idx & 15;
        const int rem = idx >> 4;
        const int h   = rem & 7;
        const int pos = (rem >> 3) & 8191;
        const int b   = rem >> 16;
        const bool cov = (h < 3) || ((h < 6) ? ((pos & 1) == 1) : ((pos & 3) == 2));
        float4 o;
        if (cov) {
            const float4 v = ((const float4*)out)[idx];
            const float4 f = ((const float4*)inv)[b * 128 + h * 16 + d4];
            o = make_float4(v.x * f.x, v.y * f.y, v.z * f.z, v.w * f.w);
        } else {
            o = make_float4(0.f, 0.f, 0.f, 0.f);
        }
        ((float4*)out)[idx] = o;
    }
}

extern "C" void kernel_launch(void* const* d_in, const int* in_sizes, int n_in,
                              void* d_out, int out_size, void* d_ws, size_t ws_size,
                              hipStream_t stream)
{
    const float* Q = (const float*)d_in[0];
    const float* K = (const float*)d_in[1];
    const float* V = (const float*)d_in[2];
    float* out      = (float*)d_out;
    float* partials = (float*)d_ws;                              // 1792*192*4 ≈ 1.4 MB
    float* partial2 = partials + (size_t)N_WAVES_P1 * NPART_STRIDE; // +16384 floats
    float* inv      = partial2 + 256 * 64;                       // +2048 floats

    hipLaunchKernelGGL(sda_pass1,  dim3(N_BLOCKS_P1), dim3(256), 0, stream,
                       Q, K, V, out, partials);
    hipLaunchKernelGGL(sda_pass2a, dim3(256), dim3(256), 0, stream, partials, partial2);
    hipLaunchKernelGGL(sda_pass2b, dim3(8),   dim3(256), 0, stream, partial2, inv);
    hipLaunchKernelGGL(sda_pass3,  dim3(2048), dim3(256), 0, stream, out, inv);
}